// Round 9
// baseline (255.600 us; speedup 1.0000x reference)
//
#include <hip/hip_runtime.h>
#include <math.h>

typedef _Float16 f16;
typedef _Float16 half8 __attribute__((ext_vector_type(8)));
typedef float floatx16 __attribute__((ext_vector_type(16)));
typedef unsigned int u32;

#define HW_     3136
#define NPC     50176.0f
#define PB      3364            // 58*58 padded pixels per image
#define PPLANE  53824           // 16 images * PB (chunks per k2-plane)
#define ASTRIDE (2 * PPLANE * 16)   // bytes between s-steps (k2 += 2) = 1722368

// LDS scalar swizzle (conflict-free both phases; verified)
#define SW(c, px) (((px) + ((c) >> 2) + ((c) & 3) * 8) & 63)

// async 16B global->LDS copy (lane L lands at wave-uniform ldsbase + L*16)
typedef __attribute__((address_space(3))) u32 lds_u32;
typedef __attribute__((address_space(1))) u32 glb_u32;
__device__ __forceinline__ void async_copy16(const void* g, void* l) {
    __builtin_amdgcn_global_load_lds((const glb_u32*)g, (lds_u32*)l, 16, 0, 0);
}

// ---------------------------------------------------------------------------
// prelude: pack (0..783, R5 px-minor form) + prep (784..927) + pad (928..1383).
// Zeroes stats (512 f) and both semaphore counters each graph iteration.
// ---------------------------------------------------------------------------
__global__ __launch_bounds__(256) void prelude_kernel(
        const float* __restrict__ x, char* __restrict__ X2,
        const float* __restrict__ w1, const float* __restrict__ wa1,
        const float* __restrict__ w2, const float* __restrict__ wa2,
        f16* __restrict__ W2a, f16* __restrict__ W2b,
        float* __restrict__ stats, u32* __restrict__ cnt) {
    const int t = threadIdx.x;
    if (blockIdx.x < 784) {
        // ---- pack: x fp32 [b][c][hw] -> X2 hi/lo fp16 chunks ----
        const int blk = blockIdx.x;
        if (blk == 0) {
            if (t < 512) stats[t] = 0.f;
            if (t == 0) { cnt[0] = 0u; cnt[1] = 0u; }
        }
        const int b = blk / 49;
        const int p0 = (blk - b * 49) * 64;
        const int px = t & 63;
        const int cq = t >> 6;
        const int p = p0 + px;
        const int h = p / 56;
        const int w = p - h * 56;
        const size_t pp = (size_t)b * PB + (h + 1) * 58 + (w + 1);
        const float* xb = x + (size_t)b * 128 * HW_ + p;
#pragma unroll
        for (int s = 0; s < 4; ++s) {
            const int cg = s * 4 + cq;              // 0..15
            half8 hv, lv;
#pragma unroll
            for (int j = 0; j < 8; ++j) {
                const float v = xb[(size_t)(cg * 8 + j) * HW_];
                const f16 hh = (f16)v;
                hv[j] = hh;
                lv[j] = (f16)(v - (float)hh);
            }
            *(half8*)(X2 + ((size_t)cg * PPLANE + pp) * 16) = hv;
            *(half8*)(X2 + ((size_t)(cg + 16) * PPLANE + pp) * 16) = lv;
        }
    } else if (blockIdx.x < 928) {
        // ---- prep: w -> integer-valued fp16, chunk (tap*16+k2)*128+oc ----
        const int idx = (blockIdx.x - 784) * 256 + t;   // 0..36863
        const float* w;
        const float* wa;
        f16* o;
        int m;
        if (idx < 18432) { w = w1; wa = wa1; o = W2a; m = idx; }
        else             { w = w2; wa = wa2; o = W2b; m = idx - 18432; }
        const int tap = m >> 11;
        const int r = m & 2047;
        const int k2 = r >> 7;
        const int oc = r & 127;
        const float a = wa[tap];
        const float* src = w + ((size_t)(tap * 128 + oc) * 128 + k2 * 8);
        half8 hv;
#pragma unroll
        for (int j = 0; j < 8; ++j)
            hv[j] = (f16)rintf(fminf(fmaxf(src[j] / a, -4.f), 3.f));
        *(half8*)(o + (size_t)m * 8) = hv;
    } else {
        // ---- pad: zero the spatial border chunks of X2 ----
        const int m = (blockIdx.x - 928) * 256 + t;    // 0..116735 = 32*16*228
        const int k2 = m / 3648;
        const int r = m - k2 * 3648;
        const int b = r / 228;
        const int j = r - b * 228;
        int h, w;
        if (j < 58)        { h = 0;  w = j; }
        else if (j < 116)  { h = 57; w = j - 58; }
        else { const int k = j - 116; h = 1 + (k >> 1); w = (k & 1) * 57; }
        const size_t chunk = (size_t)k2 * PPLANE + (size_t)b * PB + h * 58 + w;
        float4 z = {0.f, 0.f, 0.f, 0.f};
        *(float4*)(X2 + chunk * 16) = z;
    }
}

// ---------------------------------------------------------------------------
// conv phase: EXACT round-5 verified 50us structure, EXCEPT the epilogue
// writes facc into LDS (xs, swizzled) instead of global cbuf — the cbuf
// HBM round-trip (25.7MB W + 25.7MB R per conv) is deleted.
// smem: Bls 2x32KB @0 (reused as xs[2][128c x 64px] after tap 8), red @65536.
// Wave wm IS the 64-px unit index; px-in-unit = mt*32 + C/D row.
// ---------------------------------------------------------------------------
__device__ __forceinline__ int conv_phase_lds(
        const char* __restrict__ X2, const char* __restrict__ W2,
        const float* __restrict__ wav, const float* __restrict__ pav,
        float* __restrict__ stats, char* smem) {
    f16 (*Bls)[16384] = (f16 (*)[16384])smem;
    float* red = (float*)(smem + 65536);
    const int t = threadIdx.x;
    const int lane = t & 63;
    const int wv = t >> 6;
    const int wm = wv & 1, wn = wv >> 1;
    const int tile = (blockIdx.x & 7) * 49 + (blockIdx.x >> 3);  // XCD swizzle
    const int kh = lane >> 5;
    const int ln = lane & 31;

    int ppad[2];
#pragma unroll
    for (int mt = 0; mt < 2; ++mt) {
        const int gp = tile * 128 + wm * 64 + mt * 32 + ln;
        const int b = gp / HW_;
        const int p = gp - b * HW_;
        const int h = p / 56;
        const int w = p - h * 56;
        ppad[mt] = b * PB + (h + 1) * 58 + (w + 1);
    }
    int bdsoff[2];
#pragma unroll
    for (int nt = 0; nt < 2; ++nt)
        bdsoff[nt] = (kh * 128 + wn * 64 + nt * 32 + ln) * 16;
    const int sbase = wv * 8;

    floatx16 facc[2][2];
#pragma unroll
    for (int mt = 0; mt < 2; ++mt)
#pragma unroll
        for (int nt = 0; nt < 2; ++nt)
#pragma unroll
            for (int r = 0; r < 16; ++r) facc[mt][nt][r] = 0.f;

    // ---- prologue: stage tap0 B into buf0; fill A chunks 0..7 (tap0) ----
#pragma unroll
    for (int i = 0; i < 8; ++i)
        async_copy16(W2 + (((sbase + i) * 64 + lane) << 4),
                     (void*)&Bls[0][(sbase + i) * 512]);
    int aoff[2], aoffn[2];
#pragma unroll
    for (int mt = 0; mt < 2; ++mt) {
        aoff[mt] = ((ppad[mt] - 59) + kh * PPLANE) << 4;   // tap0: di=-1,dj=-1
        aoffn[mt] = aoff[mt];
    }
    half8 afr[2][8];
#pragma unroll
    for (int s0 = 0; s0 < 8; ++s0)
#pragma unroll
        for (int mt = 0; mt < 2; ++mt)
            afr[mt][s0] = *(const half8*)(X2 + aoff[mt] + s0 * ASTRIDE);
    __syncthreads();    // fences tap0 B staging

    for (int tap = 0; tap < 9; ++tap) {
        const float pak = pav[tap];
        const float s1 = wav[tap] / pak;
        const char* bcur = (const char*)&Bls[tap & 1][0];
        if (tap < 8) {
            const char* wt = W2 + (tap + 1) * 32768;
            f16* bnxt = &Bls[(tap + 1) & 1][0];
#pragma unroll
            for (int i = 0; i < 8; ++i)
                async_copy16(wt + (((sbase + i) * 64 + lane) << 4),
                             (void*)&bnxt[(sbase + i) * 512]);
            const int dn = ((tap + 1) % 3 - 1) * 58 + ((tap + 1) / 3 - 1);
#pragma unroll
            for (int mt = 0; mt < 2; ++mt)
                aoffn[mt] = ((ppad[mt] + dn) + kh * PPLANE) << 4;
        }
        half8 bds[2][2];
#pragma unroll
        for (int nt = 0; nt < 2; ++nt)
#pragma unroll
            for (int sl = 0; sl < 2; ++sl)
                bds[nt][sl] = *(const half8*)(bcur + sl * 4096 + bdsoff[nt]);

        floatx16 acc[2][2];
#pragma unroll
        for (int mt = 0; mt < 2; ++mt)
#pragma unroll
            for (int nt = 0; nt < 2; ++nt)
#pragma unroll
                for (int r = 0; r < 16; ++r) acc[mt][nt][r] = 0.f;

#pragma unroll
        for (int s = 0; s < 16; ++s) {
#pragma unroll
            for (int nt = 0; nt < 2; ++nt)
#pragma unroll
                for (int mt = 0; mt < 2; ++mt)
                    acc[mt][nt] = __builtin_amdgcn_mfma_f32_32x32x16_f16(
                        afr[mt][s & 7], bds[nt][s & 1], acc[mt][nt], 0, 0, 0);
            if (s <= 13) {
                const int kf2 = (s + 2) & 7;
#pragma unroll
                for (int nt = 0; nt < 2; ++nt)
                    bds[nt][s & 1] =
                        *(const half8*)(bcur + kf2 * 4096 + bdsoff[nt]);
            }
            if (s < 8) {
#pragma unroll
                for (int mt = 0; mt < 2; ++mt)
                    afr[mt][s & 7] =
                        *(const half8*)(X2 + aoff[mt] + (s + 8) * ASTRIDE);
            } else if (tap < 8) {
#pragma unroll
                for (int mt = 0; mt < 2; ++mt)
                    afr[mt][s & 7] =
                        *(const half8*)(X2 + aoffn[mt] + (s - 8) * ASTRIDE);
            }
        }

#pragma unroll
        for (int mt = 0; mt < 2; ++mt)
#pragma unroll
            for (int nt = 0; nt < 2; ++nt)
#pragma unroll
                for (int r = 0; r < 16; ++r) {
                    const float q = rintf(__builtin_amdgcn_fmed3f(
                        acc[mt][nt][r] * s1, -128.f, 127.f));
                    facc[mt][nt][r] = fmaf(q, pak, facc[mt][nt][r]);
                }
        aoff[0] = aoffn[0];
        aoff[1] = aoffn[1];
        __syncthreads();   // also fences: all Bls reads done before xs reuse
    }

    // epilogue: facc -> xs (LDS, swizzled). unit = wm; px = mt*32 + row.
    float* xs = (float*)smem;              // reuses Bls (free after tap 8)
    float* xu = xs + wm * 8192;            // 32KB per unit
    const int ocb = wn * 64 + ln;
#pragma unroll
    for (int mt = 0; mt < 2; ++mt)
#pragma unroll
        for (int r = 0; r < 16; ++r) {
            const int row = (r & 3) + 8 * (r >> 2) + 4 * kh;
            const int px = mt * 32 + row;
            xu[ocb * 64 + SW(ocb, px)]             = facc[mt][0][r];
            xu[(ocb + 32) * 64 + SW(ocb + 32, px)] = facc[mt][1][r];
        }

    // fused BN stats
    float sv[2], qv[2];
#pragma unroll
    for (int nt = 0; nt < 2; ++nt) {
        float s = 0.f, q = 0.f;
#pragma unroll
        for (int mt = 0; mt < 2; ++mt)
#pragma unroll
            for (int r = 0; r < 16; ++r) {
                const float v = facc[mt][nt][r];
                s += v;
                q = fmaf(v, v, q);
            }
        s += __shfl_xor(s, 32, 64);
        q += __shfl_xor(q, 32, 64);
        sv[nt] = s; qv[nt] = q;
    }
    if (lane < 32) {
#pragma unroll
        for (int nt = 0; nt < 2; ++nt) {
            const int oc = wn * 64 + nt * 32 + lane;
            red[oc * 2 + wm] = sv[nt];
            red[256 + oc * 2 + wm] = qv[nt];
        }
    }
    __syncthreads();
    if (t < 128) {
        atomicAdd(&stats[t],       red[2 * t] + red[2 * t + 1]);
        atomicAdd(&stats[128 + t], red[256 + 2 * t] + red[256 + 2 * t + 1]);
    }
    return tile;
}

// ---------------------------------------------------------------------------
// semaphore: all 392 blocks' stats atomics globally done. R7-verified pattern.
// All blocks co-resident (2/CU via launch_bounds + 132KB LDS) -> no deadlock.
// Replay-stale counters only skew profiling passes, never deadlock.
// ---------------------------------------------------------------------------
__device__ __forceinline__ void stats_semaphore(u32* cnt) {
    asm volatile("s_waitcnt vmcnt(0)" ::: "memory");   // drain own atomics
    __syncthreads();
    if (threadIdx.x == 0) {
        __hip_atomic_fetch_add(cnt, 1u, __ATOMIC_RELAXED,
                               __HIP_MEMORY_SCOPE_AGENT);
        while (__hip_atomic_load(cnt, __ATOMIC_RELAXED,
                                 __HIP_MEMORY_SCOPE_AGENT) < 392u)
            __builtin_amdgcn_s_sleep(8);
    }
    __syncthreads();
}

// BN coeffs into red region (stats via coherent atomic loads)
__device__ __forceinline__ void bn_coeffs(
        const float* __restrict__ stats, const float* __restrict__ g,
        const float* __restrict__ bb, float* scs, float* shs) {
    const int t = threadIdx.x;
    if (t < 128) {
        const float s0 = __hip_atomic_load((float*)&stats[t],
                __ATOMIC_RELAXED, __HIP_MEMORY_SCOPE_AGENT);
        const float s1 = __hip_atomic_load((float*)&stats[128 + t],
                __ATOMIC_RELAXED, __HIP_MEMORY_SCOPE_AGENT);
        const float m = s0 * (1.f / NPC);
        const float var = s1 * (1.f / NPC) - m * m;
        const float inv = 1.f / sqrtf(var + 1e-5f);
        const float sc = g[t] * inv;
        scs[t] = sc;
        shs[t] = bb[t] - m * sc;
    }
    __syncthreads();
}

// ---------------------------------------------------------------------------
// conv1 + bn_split fused. Tail reads xs from LDS (no cbuf), writes X2.
// ---------------------------------------------------------------------------
__global__ __launch_bounds__(256, 2) void conv_bn_kernel(
        const char* __restrict__ X2, const char* __restrict__ W2,
        const float* __restrict__ wav, const float* __restrict__ pav,
        float* __restrict__ stats,
        const float* __restrict__ g, const float* __restrict__ bb,
        char* __restrict__ X2o, u32* __restrict__ cnt) {
    __shared__ __align__(16) char smem[67584];
    const int tile = conv_phase_lds(X2, W2, wav, pav, stats, smem);
    stats_semaphore(cnt);

    float* xs = (float*)smem;
    float* scs = (float*)(smem + 65536);
    float* shs = scs + 128;
    bn_coeffs(stats, g, bb, scs, shs);
    const int t = threadIdx.x;
    const int px = t & 63;
    const int cq = t >> 6;
#pragma unroll
    for (int u = 0; u < 2; ++u) {
        const float* xu = xs + u * 8192;
        const int blk = 2 * tile + u;
        const int b = blk / 49;
        const int p0 = (blk - b * 49) * 64;
        const int p = p0 + px;
        const int h = p / 56;
        const int w = p - h * 56;
        const size_t pp = (size_t)b * PB + (h + 1) * 58 + (w + 1);
#pragma unroll
        for (int s = 0; s < 4; ++s) {
            const int cg = s * 4 + cq;
            half8 hv, lv;
#pragma unroll
            for (int j = 0; j < 8; ++j) {
                const int c = cg * 8 + j;
                const float v = fmaxf(
                    fmaf(xu[c * 64 + SW(c, px)], scs[c], shs[c]), 0.f);
                const f16 hh = (f16)v;
                hv[j] = hh;
                lv[j] = (f16)(v - (float)hh);
            }
            *(half8*)(X2o + ((size_t)cg * PPLANE + pp) * 16) = hv;
            *(half8*)(X2o + ((size_t)(cg + 16) * PPLANE + pp) * 16) = lv;
        }
    }
}

// ---------------------------------------------------------------------------
// conv2 + final fused. Tail reads xs from LDS, adds residual, writes out.
// Vectorized float4 resid/out (quad-px per lane).
// ---------------------------------------------------------------------------
__global__ __launch_bounds__(256, 2) void conv_final_kernel(
        const char* __restrict__ X2, const char* __restrict__ W2,
        const float* __restrict__ wav, const float* __restrict__ pav,
        float* __restrict__ stats,
        const float* __restrict__ g, const float* __restrict__ bb,
        const float* __restrict__ resid, float* __restrict__ out,
        u32* __restrict__ cnt) {
    __shared__ __align__(16) char smem[67584];
    const int tile = conv_phase_lds(X2, W2, wav, pav, stats, smem);
    stats_semaphore(cnt);

    float* xs = (float*)smem;
    float* scs = (float*)(smem + 65536);
    float* shs = scs + 128;
    bn_coeffs(stats, g, bb, scs, shs);
    const int t = threadIdx.x;
    const int l = t & 15;                        // px-quad 0..15
    const int wq = t >> 4;                       // 0..15
    const int px0 = l * 4;
#pragma unroll
    for (int u = 0; u < 2; ++u) {
        const float* xu = xs + u * 8192;
        const int blk = 2 * tile + u;
        const int b = blk / 49;
        const int p0 = (blk - b * 49) * 64;
#pragma unroll
        for (int i = 0; i < 8; ++i) {
            const int c = i * 16 + wq;
            const float sc = scs[c], sh = shs[c];
            const size_t gi = (size_t)(b * 128 + c) * HW_ + p0 + px0;
            const float4 r = *(const float4*)&resid[gi];
            float4 o;
            o.x = fmaxf(fmaf(xu[c * 64 + SW(c, px0 + 0)], sc, sh) + r.x, 0.f);
            o.y = fmaxf(fmaf(xu[c * 64 + SW(c, px0 + 1)], sc, sh) + r.y, 0.f);
            o.z = fmaxf(fmaf(xu[c * 64 + SW(c, px0 + 2)], sc, sh) + r.z, 0.f);
            o.w = fmaxf(fmaf(xu[c * 64 + SW(c, px0 + 3)], sc, sh) + r.w, 0.f);
            *(float4*)&out[gi] = o;
        }
    }
}

// ---------------------------------------------------------------------------
extern "C" void kernel_launch(void* const* d_in, const int* in_sizes, int n_in,
                              void* d_out, int out_size, void* d_ws, size_t ws_size,
                              hipStream_t stream) {
    const float* x   = (const float*)d_in[0];
    const float* w1  = (const float*)d_in[1];
    const float* wa1 = (const float*)d_in[2];
    const float* pa1 = (const float*)d_in[3];
    const float* g1  = (const float*)d_in[4];
    const float* b1  = (const float*)d_in[5];
    const float* w2  = (const float*)d_in[6];
    const float* wa2 = (const float*)d_in[7];
    const float* pa2 = (const float*)d_in[8];
    const float* g2  = (const float*)d_in[9];
    const float* b2  = (const float*)d_in[10];
    float* out = (float*)d_out;

    // ws layout (bytes):  (cbuf DELETED)
    //   X2    @ 0          : 27,557,888  (32 planes * 53824 chunks * 16 B)
    //   W2a   @ 27,557,888 :    294,912
    //   W2b   @ 27,852,800 :    294,912
    //   stats @ 28,147,712 :      2,048  (stats1 256 f + stats2 256 f)
    //   cnt   @ 28,149,760 :          8  (semaphore counters)
    char* ws = (char*)d_ws;
    char*  X2    = ws;
    f16*   W2a   = (f16*)(ws + 27557888);
    f16*   W2b   = (f16*)(ws + 27852800);
    float* stats = (float*)(ws + 28147712);
    u32*   cnt   = (u32*)(ws + 28149760);
    float* stats1 = stats;
    float* stats2 = stats + 256;

    hipLaunchKernelGGL(prelude_kernel, dim3(1384), dim3(256), 0, stream,
                       x, X2, w1, wa1, w2, wa2, W2a, W2b, stats, cnt);
    hipLaunchKernelGGL(conv_bn_kernel, dim3(392), dim3(256), 0, stream,
                       X2, (const char*)W2a, wa1, pa1, stats1,
                       g1, b1, X2, cnt);
    hipLaunchKernelGGL(conv_final_kernel, dim3(392), dim3(256), 0, stream,
                       X2, (const char*)W2b, wa2, pa2, stats2,
                       g2, b2, x, out, cnt + 1);
}

// Round 10
// 205.589 us; speedup vs baseline: 1.2433x; 1.2433x over previous
//
#include <hip/hip_runtime.h>
#include <math.h>

typedef _Float16 f16;
typedef _Float16 half8 __attribute__((ext_vector_type(8)));
typedef float floatx16 __attribute__((ext_vector_type(16)));
typedef unsigned int u32;

#define HW_     3136
#define NPC     50176.0f
#define PB      3364            // 58*58 padded pixels per image
#define PPLANE  53824           // 16 images * PB (chunks per k2-plane)
#define ASTRIDE (2 * PPLANE * 16)   // bytes between s-steps (k2 += 2) = 1722368

// LDS scalar swizzle (conflict-free both phases; verified)
#define SW(c, px) (((px) + ((c) >> 2) + ((c) & 3) * 8) & 63)

// async 16B global->LDS copy (lane L lands at wave-uniform ldsbase + L*16)
typedef __attribute__((address_space(3))) u32 lds_u32;
typedef __attribute__((address_space(1))) u32 glb_u32;
__device__ __forceinline__ void async_copy16(const void* g, void* l) {
    __builtin_amdgcn_global_load_lds((const glb_u32*)g, (lds_u32*)l, 16, 0, 0);
}

// ---------------------------------------------------------------------------
// prelude: pack (0..783) + prep (784..927) + pad (928..1383). R5-exact.
// ---------------------------------------------------------------------------
__global__ __launch_bounds__(256) void prelude_kernel(
        const float* __restrict__ x, char* __restrict__ X2,
        const float* __restrict__ w1, const float* __restrict__ wa1,
        const float* __restrict__ w2, const float* __restrict__ wa2,
        f16* __restrict__ W2a, f16* __restrict__ W2b,
        float* __restrict__ stats) {
    const int t = threadIdx.x;
    if (blockIdx.x < 784) {
        // ---- pack: x fp32 [b][c][hw] -> X2 hi/lo fp16 chunks ----
        const int blk = blockIdx.x;
        if (blk == 0 && t < 512) stats[t] = 0.f;    // zero stats1+stats2
        const int b = blk / 49;
        const int p0 = (blk - b * 49) * 64;
        const int px = t & 63;
        const int cq = t >> 6;
        const int p = p0 + px;
        const int h = p / 56;
        const int w = p - h * 56;
        const size_t pp = (size_t)b * PB + (h + 1) * 58 + (w + 1);
        const float* xb = x + (size_t)b * 128 * HW_ + p;
#pragma unroll
        for (int s = 0; s < 4; ++s) {
            const int cg = s * 4 + cq;              // 0..15
            half8 hv, lv;
#pragma unroll
            for (int j = 0; j < 8; ++j) {
                const float v = xb[(size_t)(cg * 8 + j) * HW_];
                const f16 hh = (f16)v;
                hv[j] = hh;
                lv[j] = (f16)(v - (float)hh);
            }
            *(half8*)(X2 + ((size_t)cg * PPLANE + pp) * 16) = hv;
            *(half8*)(X2 + ((size_t)(cg + 16) * PPLANE + pp) * 16) = lv;
        }
    } else if (blockIdx.x < 928) {
        // ---- prep: w -> integer-valued fp16, chunk (tap*16+k2)*128+oc ----
        const int idx = (blockIdx.x - 784) * 256 + t;   // 0..36863
        const float* w;
        const float* wa;
        f16* o;
        int m;
        if (idx < 18432) { w = w1; wa = wa1; o = W2a; m = idx; }
        else             { w = w2; wa = wa2; o = W2b; m = idx - 18432; }
        const int tap = m >> 11;
        const int r = m & 2047;
        const int k2 = r >> 7;
        const int oc = r & 127;
        const float a = wa[tap];
        const float* src = w + ((size_t)(tap * 128 + oc) * 128 + k2 * 8);
        half8 hv;
#pragma unroll
        for (int j = 0; j < 8; ++j)
            hv[j] = (f16)rintf(fminf(fmaxf(src[j] / a, -4.f), 3.f));
        *(half8*)(o + (size_t)m * 8) = hv;
    } else {
        // ---- pad: zero the spatial border chunks of X2 ----
        const int m = (blockIdx.x - 928) * 256 + t;    // 0..116735 = 32*16*228
        const int k2 = m / 3648;
        const int r = m - k2 * 3648;
        const int b = r / 228;
        const int j = r - b * 228;
        int h, w;
        if (j < 58)        { h = 0;  w = j; }
        else if (j < 116)  { h = 57; w = j - 58; }
        else { const int k = j - 116; h = 1 + (k >> 1); w = (k & 1) * 57; }
        const size_t chunk = (size_t)k2 * PPLANE + (size_t)b * PB + h * 58 + w;
        float4 z = {0.f, 0.f, 0.f, 0.f};
        *(float4*)(X2 + chunk * 16) = z;
    }
}

// ---------------------------------------------------------------------------
// conv: R5 verified 50us structure. ONE change (T4 counted-vmcnt barrier):
// the per-tap __syncthreads (= s_waitcnt vmcnt(0) lgkmcnt(0) + s_barrier,
// draining the 16 in-flight A-refill loads every tap) is replaced by
// s_waitcnt vmcnt(16) lgkmcnt(0) + s_barrier. vmcnt(16) drains each wave's
// OWN 8 staging global_load_lds (oldest in its FIFO) while leaving its 16
// younger A-refill loads in flight across the barrier. After the barrier,
// ALL waves' staging for the next tap is complete (each drained its own
// before arriving), so the next tap's B prefill is safe; A-refill uses get
// compiler-inserted vmcnt waits as before.
// ---------------------------------------------------------------------------
__global__ __launch_bounds__(256, 2) void conv_kernel(
        const char* __restrict__ X2, const char* __restrict__ W2,
        const float* __restrict__ wav, const float* __restrict__ pav,
        float* __restrict__ cbuf, float* __restrict__ stats) {
    __shared__ f16 Bls[2][16384];    // 2 x 32 KB (chunk-major, W2 tap order)
    __shared__ float red[512];
    const int t = threadIdx.x;
    const int lane = t & 63;
    const int wv = t >> 6;
    const int wm = wv & 1, wn = wv >> 1;
    const int tile = (blockIdx.x & 7) * 49 + (blockIdx.x >> 3);  // XCD swizzle
    const int kh = lane >> 5;
    const int ln = lane & 31;

    int ppad[2];
#pragma unroll
    for (int mt = 0; mt < 2; ++mt) {
        const int gp = tile * 128 + wm * 64 + mt * 32 + ln;
        const int b = gp / HW_;
        const int p = gp - b * HW_;
        const int h = p / 56;
        const int w = p - h * 56;
        ppad[mt] = b * PB + (h + 1) * 58 + (w + 1);
    }
    int bdsoff[2];
#pragma unroll
    for (int nt = 0; nt < 2; ++nt)
        bdsoff[nt] = (kh * 128 + wn * 64 + nt * 32 + ln) * 16;
    const int sbase = wv * 8;

    floatx16 facc[2][2];
#pragma unroll
    for (int mt = 0; mt < 2; ++mt)
#pragma unroll
        for (int nt = 0; nt < 2; ++nt)
#pragma unroll
            for (int r = 0; r < 16; ++r) facc[mt][nt][r] = 0.f;

    // ---- prologue: stage tap0 B into buf0; fill A chunks 0..7 (tap0) ----
#pragma unroll
    for (int i = 0; i < 8; ++i)
        async_copy16(W2 + (((sbase + i) * 64 + lane) << 4),
                     (void*)&Bls[0][(sbase + i) * 512]);
    int aoff[2], aoffn[2];
#pragma unroll
    for (int mt = 0; mt < 2; ++mt) {
        aoff[mt] = ((ppad[mt] - 59) + kh * PPLANE) << 4;   // tap0: di=-1,dj=-1
        aoffn[mt] = aoff[mt];
    }
    half8 afr[2][8];
#pragma unroll
    for (int s0 = 0; s0 < 8; ++s0)
#pragma unroll
        for (int mt = 0; mt < 2; ++mt)
            afr[mt][s0] = *(const half8*)(X2 + aoff[mt] + s0 * ASTRIDE);
    __syncthreads();    // full drain ok once: fences tap0 B staging

    for (int tap = 0; tap < 9; ++tap) {
        const float pak = pav[tap];
        const float s1 = wav[tap] / pak;
        const char* bcur = (const char*)&Bls[tap & 1][0];
        if (tap < 8) {
            // stage next tap's B into the other buffer
            const char* wt = W2 + (tap + 1) * 32768;
            f16* bnxt = &Bls[(tap + 1) & 1][0];
#pragma unroll
            for (int i = 0; i < 8; ++i)
                async_copy16(wt + (((sbase + i) * 64 + lane) << 4),
                             (void*)&bnxt[(sbase + i) * 512]);
            const int dn = ((tap + 1) % 3 - 1) * 58 + ((tap + 1) / 3 - 1);
#pragma unroll
            for (int mt = 0; mt < 2; ++mt)
                aoffn[mt] = ((ppad[mt] + dn) + kh * PPLANE) << 4;
        }
        // prefill B slots for steps 0,1 (current buffer valid since barrier)
        half8 bds[2][2];
#pragma unroll
        for (int nt = 0; nt < 2; ++nt)
#pragma unroll
            for (int sl = 0; sl < 2; ++sl)
                bds[nt][sl] = *(const half8*)(bcur + sl * 4096 + bdsoff[nt]);

        floatx16 acc[2][2];
#pragma unroll
        for (int mt = 0; mt < 2; ++mt)
#pragma unroll
            for (int nt = 0; nt < 2; ++nt)
#pragma unroll
                for (int r = 0; r < 16; ++r) acc[mt][nt][r] = 0.f;

#pragma unroll
        for (int s = 0; s < 16; ++s) {
#pragma unroll
            for (int nt = 0; nt < 2; ++nt)
#pragma unroll
                for (int mt = 0; mt < 2; ++mt)
                    acc[mt][nt] = __builtin_amdgcn_mfma_f32_32x32x16_f16(
                        afr[mt][s & 7], bds[nt][s & 1], acc[mt][nt], 0, 0, 0);
            // B rotation refill (current buffer only; steps 14,15 pre-written)
            if (s <= 13) {
                const int kf2 = (s + 2) & 7;
#pragma unroll
                for (int nt = 0; nt < 2; ++nt)
                    bds[nt][s & 1] =
                        *(const half8*)(bcur + kf2 * 4096 + bdsoff[nt]);
            }
            // A rotation refill: within-tap chunks 8..15, then next tap 0..7
            if (s < 8) {
#pragma unroll
                for (int mt = 0; mt < 2; ++mt)
                    afr[mt][s & 7] =
                        *(const half8*)(X2 + aoff[mt] + (s + 8) * ASTRIDE);
            } else if (tap < 8) {
#pragma unroll
                for (int mt = 0; mt < 2; ++mt)
                    afr[mt][s & 7] =
                        *(const half8*)(X2 + aoffn[mt] + (s - 8) * ASTRIDE);
            }
        }

        // per-tap 8-bit LSQ quantize of the partial sum, accumulate
#pragma unroll
        for (int mt = 0; mt < 2; ++mt)
#pragma unroll
            for (int nt = 0; nt < 2; ++nt)
#pragma unroll
                for (int r = 0; r < 16; ++r) {
                    const float q = rintf(__builtin_amdgcn_fmed3f(
                        acc[mt][nt][r] * s1, -128.f, 127.f));
                    facc[mt][nt][r] = fmaf(q, pak, facc[mt][nt][r]);
                }
        aoff[0] = aoffn[0];
        aoff[1] = aoffn[1];
        // T4 counted-drain barrier: own staging (8, oldest) drained; own 16
        // A-refills stay in flight across the barrier.
        asm volatile("s_waitcnt vmcnt(16) lgkmcnt(0)" ::: "memory");
        __builtin_amdgcn_s_barrier();
    }

    // epilogue: cbuf [gp][oc] fp32  (32x32 C/D: row=(r&3)+8*(r>>2)+4*kh, col=ln)
    const int gpb = tile * 128 + wm * 64;
    const int ocb = wn * 64 + ln;
#pragma unroll
    for (int mt = 0; mt < 2; ++mt)
#pragma unroll
        for (int r = 0; r < 16; ++r) {
            const int row = (r & 3) + 8 * (r >> 2) + 4 * kh;
            const int gp = gpb + mt * 32 + row;
            float* rp = cbuf + (size_t)gp * 128 + ocb;
            rp[0]  = facc[mt][0][r];
            rp[32] = facc[mt][1][r];
        }

    // fused BN stats
    float sv[2], qv[2];
#pragma unroll
    for (int nt = 0; nt < 2; ++nt) {
        float s = 0.f, q = 0.f;
#pragma unroll
        for (int mt = 0; mt < 2; ++mt)
#pragma unroll
            for (int r = 0; r < 16; ++r) {
                const float v = facc[mt][nt][r];
                s += v;
                q = fmaf(v, v, q);
            }
        s += __shfl_xor(s, 32, 64);
        q += __shfl_xor(q, 32, 64);
        sv[nt] = s; qv[nt] = q;
    }
    if (lane < 32) {
#pragma unroll
        for (int nt = 0; nt < 2; ++nt) {
            const int oc = wn * 64 + nt * 32 + lane;
            red[oc * 2 + wm] = sv[nt];
            red[256 + oc * 2 + wm] = qv[nt];
        }
    }
    __syncthreads();
    if (t < 128) {
        atomicAdd(&stats[t],       red[2 * t] + red[2 * t + 1]);
        atomicAdd(&stats[128 + t], red[256 + 2 * t] + red[256 + 2 * t + 1]);
    }
}

// ---------------------------------------------------------------------------
// bn_split: cbuf fp32 [gp][oc] -> bn+relu -> X2 hi/lo packed. R5-exact.
// ---------------------------------------------------------------------------
__global__ __launch_bounds__(256) void bn_split_kernel(
        const float* __restrict__ cbuf, const float* __restrict__ stats,
        const float* __restrict__ g, const float* __restrict__ bb,
        char* __restrict__ X2) {
    __shared__ float xs[8192];
    __shared__ float scs[128], shs[128];
    const int t = threadIdx.x;
    if (t < 128) {
        const float m = stats[t] * (1.f / NPC);
        const float var = stats[128 + t] * (1.f / NPC) - m * m;
        const float inv = 1.f / sqrtf(var + 1e-5f);
        const float sc = g[t] * inv;
        scs[t] = sc;
        shs[t] = bb[t] - m * sc;
    }
    __syncthreads();
    const int blk = blockIdx.x;                  // 784
#pragma unroll
    for (int i = 0; i < 8; ++i) {
        const int idx = i * 256 + t;
        const int px = idx >> 5;
        const int q = idx & 31;
        const float4 v = *(const float4*)&cbuf[(size_t)(blk * 64 + px) * 128 + q * 4];
        const float vv[4] = {v.x, v.y, v.z, v.w};
#pragma unroll
        for (int j = 0; j < 4; ++j) {
            const int c = q * 4 + j;
            xs[c * 64 + SW(c, px)] = fmaxf(fmaf(vv[j], scs[c], shs[c]), 0.f);
        }
    }
    __syncthreads();
    const int b = blk / 49;
    const int p0 = (blk - b * 49) * 64;
    const int px = t & 63;
    const int cq = t >> 6;
    const int p = p0 + px;
    const int h = p / 56;
    const int w = p - h * 56;
    const size_t pp = (size_t)b * PB + (h + 1) * 58 + (w + 1);
#pragma unroll
    for (int s = 0; s < 4; ++s) {
        const int cg = s * 4 + cq;
        half8 hv, lv;
#pragma unroll
        for (int j = 0; j < 8; ++j) {
            const int c = cg * 8 + j;
            const float v = xs[c * 64 + SW(c, px)];
            const f16 hh = (f16)v;
            hv[j] = hh;
            lv[j] = (f16)(v - (float)hh);
        }
        *(half8*)(X2 + ((size_t)cg * PPLANE + pp) * 16) = hv;
        *(half8*)(X2 + ((size_t)(cg + 16) * PPLANE + pp) * 16) = lv;
    }
}

// ---------------------------------------------------------------------------
// final: bn2 + residual add + relu, [gp][oc] -> [b][c][hw]. R5-exact.
// ---------------------------------------------------------------------------
__global__ __launch_bounds__(256) void final_kernel(
        const float* __restrict__ cbuf, const float* __restrict__ stats,
        const float* __restrict__ g, const float* __restrict__ bb,
        const float* __restrict__ resid, float* __restrict__ out) {
    __shared__ float xs[8192];
    __shared__ float scs[128], shs[128];
    const int t = threadIdx.x;
    if (t < 128) {
        const float m = stats[t] * (1.f / NPC);
        const float var = stats[128 + t] * (1.f / NPC) - m * m;
        const float inv = 1.f / sqrtf(var + 1e-5f);
        const float sc = g[t] * inv;
        scs[t] = sc;
        shs[t] = bb[t] - m * sc;
    }
    __syncthreads();
    const int blk = blockIdx.x;                  // 784
#pragma unroll
    for (int i = 0; i < 8; ++i) {
        const int idx = i * 256 + t;
        const int px = idx >> 5;
        const int q = idx & 31;
        const float4 v = *(const float4*)&cbuf[(size_t)(blk * 64 + px) * 128 + q * 4];
        const float vv[4] = {v.x, v.y, v.z, v.w};
#pragma unroll
        for (int j = 0; j < 4; ++j) {
            const int c = q * 4 + j;
            xs[c * 64 + SW(c, px)] = fmaf(vv[j], scs[c], shs[c]);
        }
    }
    __syncthreads();
    const int b = blk / 49;
    const int p0 = (blk - b * 49) * 64;
    const int lane = t & 63, wq = t >> 6;
#pragma unroll
    for (int i = 0; i < 32; ++i) {
        const int c = i * 4 + wq;
        const float v = xs[c * 64 + SW(c, lane)];
        const size_t gi = (size_t)(b * 128 + c) * HW_ + p0 + lane;
        out[gi] = fmaxf(v + resid[gi], 0.f);
    }
}

// ---------------------------------------------------------------------------
extern "C" void kernel_launch(void* const* d_in, const int* in_sizes, int n_in,
                              void* d_out, int out_size, void* d_ws, size_t ws_size,
                              hipStream_t stream) {
    const float* x   = (const float*)d_in[0];
    const float* w1  = (const float*)d_in[1];
    const float* wa1 = (const float*)d_in[2];
    const float* pa1 = (const float*)d_in[3];
    const float* g1  = (const float*)d_in[4];
    const float* b1  = (const float*)d_in[5];
    const float* w2  = (const float*)d_in[6];
    const float* wa2 = (const float*)d_in[7];
    const float* pa2 = (const float*)d_in[8];
    const float* g2  = (const float*)d_in[9];
    const float* b2  = (const float*)d_in[10];
    float* out = (float*)d_out;

    // ws layout (bytes):
    //   X2    @ 0          : 27,557,888  (32 planes * 53824 chunks * 16 B)
    //   cbuf  @ 27,557,888 : 25,690,112
    //   W2a   @ 53,248,000 :    294,912
    //   W2b   @ 53,542,912 :    294,912
    //   stats @ 53,837,824 :      2,048  (stats1 256 f + stats2 256 f)
    char* ws = (char*)d_ws;
    char*  X2    = ws;
    float* cbuf  = (float*)(ws + 27557888);
    f16*   W2a   = (f16*)(ws + 53248000);
    f16*   W2b   = (f16*)(ws + 53542912);
    float* stats = (float*)(ws + 53837824);
    float* stats1 = stats;
    float* stats2 = stats + 256;

    hipLaunchKernelGGL(prelude_kernel, dim3(1384), dim3(256), 0, stream,
                       x, X2, w1, wa1, w2, wa2, W2a, W2b, stats);
    hipLaunchKernelGGL(conv_kernel, dim3(392), dim3(256), 0, stream,
                       X2, (const char*)W2a, wa1, pa1, cbuf, stats1);
    hipLaunchKernelGGL(bn_split_kernel, dim3(784), dim3(256), 0, stream,
                       cbuf, stats1, g1, b1, X2);
    hipLaunchKernelGGL(conv_kernel, dim3(392), dim3(256), 0, stream,
                       X2, (const char*)W2b, wa2, pa2, cbuf, stats2);
    hipLaunchKernelGGL(final_kernel, dim3(784), dim3(256), 0, stream,
                       cbuf, stats2, g2, b2, x, out);
}